// Round 4
// baseline (257.985 us; speedup 1.0000x reference)
//
#include <hip/hip_runtime.h>
#include <stdint.h>

#define DIM 768
#define HEADS 12
#define SEQ 196
#define BATCH 64
#define NTOK (BATCH*SEQ)   // 12544
#define QKVLD (3*DIM)      // 2304, row stride of qkv workspace
#define SCALE 0.125f       // 64^-0.5

using short8  = __attribute__((ext_vector_type(8))) short;
using short4v = __attribute__((ext_vector_type(4))) short;
using float4v = __attribute__((ext_vector_type(4))) float;
using float16v = __attribute__((ext_vector_type(16))) float;
using ushort4v = __attribute__((ext_vector_type(4))) unsigned short;

static __device__ __forceinline__ unsigned short f2bf(float f) {
  union { float f; unsigned u; } v; v.f = f;
  unsigned u = v.u;
  u += 0x7fffu + ((u >> 16) & 1u);   // RNE
  return (unsigned short)(u >> 16);
}

#if defined(__has_builtin)
#if __has_builtin(__builtin_amdgcn_global_load_lds)
#define HAS_GLL 1
#endif
#endif

// Stage 16B/lane: global (per-lane ptr g) -> LDS (wave-uniform base l, lane*16B apart)
static __device__ __forceinline__ void gll16(const unsigned short* g, unsigned short* l) {
#ifdef HAS_GLL
  __builtin_amdgcn_global_load_lds(
      (const __attribute__((address_space(1))) void*)g,
      (__attribute__((address_space(3))) void*)l, 16, 0, 0);
#else
  const int lane = threadIdx.x & 63;
  *(short8*)(l + lane * 8) = *(const short8*)g;
#endif
}

// raw barrier (no vmcnt drain) with compiler memory-motion fences
static __device__ __forceinline__ void barx() {
  asm volatile("" ::: "memory");
  __builtin_amdgcn_s_barrier();
  asm volatile("" ::: "memory");
}
#define VMW8 asm volatile("s_waitcnt vmcnt(8)" ::: "memory")
#define VMW4 asm volatile("s_waitcnt vmcnt(4)" ::: "memory")
#define VMW0 asm volatile("s_waitcnt vmcnt(0)" ::: "memory")
// drain own ds_reads, then pin: stop MFMAs from hoisting above (rule #18)
#define LGKM0 do { asm volatile("s_waitcnt lgkmcnt(0)" ::: "memory"); \
                   __builtin_amdgcn_sched_barrier(0); } while (0)

// ---------------- pre-pass: cast x fp32 -> bf16 ----------------
__global__ __launch_bounds__(256) void cast_x_kernel(const float* __restrict__ in,
                                                     unsigned short* __restrict__ out) {
  int i = blockIdx.x * 256 + threadIdx.x;      // exactly NTOK*DIM/4 threads
  float4 v = ((const float4*)in)[i];
  ushort4v o;
  o.x = f2bf(v.x); o.y = f2bf(v.y); o.z = f2bf(v.z); o.w = f2bf(v.w);
  ((ushort4v*)out)[i] = o;
}

// ---------------- pre-pass: transpose + cast W [R][C] fp32 -> Wt [C][R] bf16 ----------------
__global__ __launch_bounds__(256) void transpose_cast_kernel(const float* __restrict__ in,
                                                             unsigned short* __restrict__ out,
                                                             int R, int C) {
  __shared__ float tile[32][33];
  int c0 = blockIdx.x * 32, r0 = blockIdx.y * 32;
  int tx = threadIdx.x, ty = threadIdx.y;      // (32,8)
  for (int i = 0; i < 32; i += 8)
    tile[ty + i][tx] = in[(size_t)(r0 + ty + i) * C + c0 + tx];
  __syncthreads();
  for (int i = 0; i < 32; i += 8)
    out[(size_t)(c0 + ty + i) * R + r0 + tx] = f2bf(tile[tx][ty + i]);
}

// ---------------- pre-pass: transpose static_a per head: saT[h][m][n] = sa[h][n][m] ----------------
__global__ __launch_bounds__(256) void transpose_sa_kernel(const float* __restrict__ in,
                                                           float* __restrict__ out) {
  __shared__ float tile[32][33];
  const int h = blockIdx.z;
  const int n0 = blockIdx.x * 32, m0 = blockIdx.y * 32;
  const int tx = threadIdx.x, ty = threadIdx.y;   // (32,8)
  const float* inh = in + (size_t)h * SEQ * SEQ;
  float* outh = out + (size_t)h * SEQ * SEQ;
  for (int i = 0; i < 32; i += 8)
    if (n0 + ty + i < SEQ && m0 + tx < SEQ)
      tile[ty + i][tx] = inh[(size_t)(n0 + ty + i) * SEQ + m0 + tx];
  __syncthreads();
  for (int i = 0; i < 32; i += 8)
    if (m0 + ty + i < SEQ && n0 + tx < SEQ)
      outh[(size_t)(m0 + ty + i) * SEQ + n0 + tx] = tile[tx][ty + i];
}

// ---------------- GEMM: C[M][N] = A[M][768] * Bt[N][768]^T ----------------
// 256x256 tile, BK=32, 8 waves (2Mx4N, wave tile 128x64 as 4x2 of 32x32),
// mfma_f32_32x32x16_bf16 (2495 TF pipe vs 2075 for 16x16), 4-deep LDS ring,
// counted vmcnt once per tile, and the FAITHFUL 8-phase rhythm (2 phases/tile):
//   phase = { <=8 ds_read_b128, 2 global_load_lds, barrier, lgkmcnt(0)+sched_pin,
//             setprio(1), 8 MFMA, setprio(0), barrier }
// so each wave's small read batch is drained while other waves' MFMA clusters
// stagger through the matrix pipes (m196/m201: this interleave is the lever).
// Swizzle: chunk ^= (row>>1)&3 on BOTH stage-source and frag reads (rule #21);
// 32-row operand reads spread uniformly over 8 (slot,parity) positions ->
// conflict-free (verified BANK_CONFLICT=0 for the same layout in r2/r3).
// MODE 0: C^T-register formulation (mfma(b,a)), bf16 out row-major [M][2304]
// MODE 1: fp32 out[m][768] + bias[n]
template <int MODE>
__global__ __launch_bounds__(512, 2) void gemm256_kernel(const unsigned short* __restrict__ A,
                                                         const unsigned short* __restrict__ Bt,
                                                         const float* __restrict__ bias,
                                                         unsigned short* __restrict__ outB,
                                                         float* __restrict__ outF) {
  constexpr int K = 768;
  constexpr int NT = 24;                               // K-tiles of 32
  __shared__ __align__(16) unsigned short Als[4][8192];   // [slot][256 rows][32 cols]
  __shared__ __align__(16) unsigned short Bls[4][8192];
  const int tid = threadIdx.x;
  const int wid = tid >> 6, lane = tid & 63;
  const int r32 = lane & 31, q5 = lane >> 5;
  const int wr = wid >> 2, wc = wid & 3;               // 2x4 wave grid, 128x64 per wave

  // XCD-aware bijective swizzle: contiguous id chunk per XCD -> panels L2-resident.
  const int nbx = gridDim.x;
  const int nb = gridDim.x * gridDim.y;
  int id = blockIdx.y * nbx + blockIdx.x;
  {
    int x = id & 7, lid = id >> 3;
    int per = nb >> 3, big = nb & 7;
    id = (x < big) ? x * (per + 1) + lid
                   : big * (per + 1) + (x - big) * per + lid;
  }
  const int m0 = (id / nbx) * 256;
  const int n0 = (id % nbx) * 256;

  // frag LDS offsets (elements), invariant across tiles. chunk = ks*2 + q5.
  auto off = [&](int row, int chunk) { return row * 32 + (((chunk) ^ ((row >> 1) & 3)) << 3); };
  const int oA00 = off(wr * 128 +  0 + r32, q5),     oA01 = off(wr * 128 +  0 + r32, 2 + q5);
  const int oA10 = off(wr * 128 + 32 + r32, q5),     oA11 = off(wr * 128 + 32 + r32, 2 + q5);
  const int oA20 = off(wr * 128 + 64 + r32, q5),     oA21 = off(wr * 128 + 64 + r32, 2 + q5);
  const int oA30 = off(wr * 128 + 96 + r32, q5),     oA31 = off(wr * 128 + 96 + r32, 2 + q5);
  const int oB00 = off(wc * 64 +  0 + r32, q5),      oB01 = off(wc * 64 +  0 + r32, 2 + q5);
  const int oB10 = off(wc * 64 + 32 + r32, q5),      oB11 = off(wc * 64 + 32 + r32, 2 + q5);

  float16v c00 = {0.f}, c01 = {0.f}, c10 = {0.f}, c11 = {0.f},
           c20 = {0.f}, c21 = {0.f}, c30 = {0.f}, c31 = {0.f};

  // Staging: thread t covers 16B chunks t and 512+t (row +128). Linear LDS dest
  // (gll requirement); SOURCE column-chunk pre-permuted by the read involution.
  const int srow = tid >> 2;                             // 0..127
  const int scol8 = (((tid & 3) ^ ((srow >> 1) & 3)) << 3);
  const unsigned short* gA = A + (size_t)(m0 + srow) * K + scol8;
  const unsigned short* gB = Bt + (size_t)(n0 + srow) * K + scol8;
  unsigned short* lA0 = &Als[0][0] + wid * 512;
  unsigned short* lB0 = &Bls[0][0] + wid * 512;

  auto stageA = [&](int t_) {
    const unsigned short* g = gA + t_ * 32;
    unsigned short* l = lA0 + (t_ & 3) * 8192;
    gll16(g, l); gll16(g + 128 * K, l + 4096);
  };
  auto stageB = [&](int t_) {
    const unsigned short* g = gB + t_ * 32;
    unsigned short* l = lB0 + (t_ & 3) * 8192;
    gll16(g, l); gll16(g + 128 * K, l + 4096);
  };

  // prologue: stage tiles 0,1,2 (tile0's 4 loads oldest); retire tile 0 only.
  stageA(0); stageB(0); stageA(1); stageB(1); stageA(2); stageB(2);
  VMW8;
  barx();

#define MM(C, AF, BF)                                                              \
  do { if (MODE == 0) C = __builtin_amdgcn_mfma_f32_32x32x16_bf16(BF, AF, C, 0, 0, 0); \
       else           C = __builtin_amdgcn_mfma_f32_32x32x16_bf16(AF, BF, C, 0, 0, 0); } while (0)

#pragma unroll 1
  for (int t = 0; t < NT; ++t) {
    const unsigned short* As = &Als[0][0] + (t & 3) * 8192;
    const unsigned short* Bs = &Bls[0][0] + (t & 3) * 8192;

    // ---- phase 0: 8 reads (A mt0-1, B all), stage A(t+3), 8 MFMA (mt0-1) ----
    short8 a00 = *(const short8*)&As[oA00], a01 = *(const short8*)&As[oA01];
    short8 a10 = *(const short8*)&As[oA10], a11 = *(const short8*)&As[oA11];
    short8 b00 = *(const short8*)&Bs[oB00], b01 = *(const short8*)&Bs[oB01];
    short8 b10 = *(const short8*)&Bs[oB10], b11 = *(const short8*)&Bs[oB11];
    if (t < NT - 3) stageA(t + 3);
    barx();
    LGKM0;
    __builtin_amdgcn_s_setprio(1);
    MM(c00, a00, b00); MM(c01, a00, b10); MM(c10, a10, b00); MM(c11, a10, b10);
    MM(c00, a01, b01); MM(c01, a01, b11); MM(c10, a11, b01); MM(c11, a11, b11);
    __builtin_amdgcn_s_setprio(0);
    barx();

    // ---- phase 1: 4 reads (A mt2-3), stage B(t+3), 8 MFMA (mt2-3) ----
    short8 a20 = *(const short8*)&As[oA20], a21 = *(const short8*)&As[oA21];
    short8 a30 = *(const short8*)&As[oA30], a31 = *(const short8*)&As[oA31];
    if (t < NT - 3) stageB(t + 3);
    barx();
    LGKM0;
    __builtin_amdgcn_s_setprio(1);
    MM(c20, a20, b00); MM(c21, a20, b10); MM(c30, a30, b00); MM(c31, a30, b10);
    MM(c20, a21, b01); MM(c21, a21, b11); MM(c30, a31, b01); MM(c31, a31, b11);
    __builtin_amdgcn_s_setprio(0);
    // counted wait (once per tile, never 0 mid-loop): tile t+1 landed; t+2,t+3 in flight
    if (t < NT - 3)      { VMW8; }
    else if (t == NT - 3){ VMW4; }
    else if (t == NT - 2){ VMW0; }
    barx();
  }
#undef MM

  // epilogue. 32x32 C/D mapping: col = lane&31, row = (j&3) + 8*(j>>2) + 4*q5.
  if (MODE == 0) {
    // T = C^T tile: row->n-local, col->m-local.
    // lane: m = m0+wr*128+mt*32+r32; n = n0+wc*64+nt*32+jg*8+q5*4+(j&3)
#define EPI0(C, MT, NT_)                                                         \
    do {                                                                         \
      size_t mrow = (size_t)(m0 + wr * 128 + (MT) * 32 + r32) * QKVLD;           \
      int nb_ = n0 + wc * 64 + (NT_) * 32 + q5 * 4;                              \
      _Pragma("unroll")                                                          \
      for (int jg = 0; jg < 4; ++jg) {                                           \
        ushort4v ov;                                                             \
        ov.x = f2bf(C[jg * 4 + 0]); ov.y = f2bf(C[jg * 4 + 1]);                  \
        ov.z = f2bf(C[jg * 4 + 2]); ov.w = f2bf(C[jg * 4 + 3]);                  \
        *(ushort4v*)&outB[mrow + nb_ + jg * 8] = ov;                             \
      }                                                                          \
    } while (0)
    EPI0(c00, 0, 0); EPI0(c01, 0, 1); EPI0(c10, 1, 0); EPI0(c11, 1, 1);
    EPI0(c20, 2, 0); EPI0(c21, 2, 1); EPI0(c30, 3, 0); EPI0(c31, 3, 1);
#undef EPI0
  } else {
    // D: row->m-local, col->n-local.
#define EPI1(C, MT, NT_)                                                         \
    do {                                                                         \
      int nn_ = n0 + wc * 64 + (NT_) * 32 + r32;                                 \
      float bv_ = bias[nn_];                                                     \
      int mb_ = m0 + wr * 128 + (MT) * 32 + q5 * 4;                              \
      _Pragma("unroll")                                                          \
      for (int jg = 0; jg < 4; ++jg)                                             \
        _Pragma("unroll")                                                        \
        for (int jj = 0; jj < 4; ++jj)                                           \
          outF[(size_t)(mb_ + jg * 8 + jj) * 768 + nn_] = C[jg * 4 + jj] + bv_;  \
    } while (0)
    EPI1(c00, 0, 0); EPI1(c01, 0, 1); EPI1(c10, 1, 0); EPI1(c11, 1, 1);
    EPI1(c20, 2, 0); EPI1(c21, 2, 1); EPI1(c30, 3, 0); EPI1(c31, 3, 1);
#undef EPI1
  }
}

// ---------------- attention: one block per (b,h), S^T formulation ----------------
// qkv workspace is [NTOK][2304] row-major. K is staged into LDS once (coalesced
// 128B global reads), XOR-swizzled so the permuted-row fragment reads are
// conflict-free-ish; static_a is pre-transposed so bias loads are lane-coalesced.
__global__ __launch_bounds__(256) void attn_kernel(const unsigned short* __restrict__ qkv,
                                                   const float* __restrict__ saT,
                                                   unsigned short* __restrict__ outA) {
  constexpr int WV = 228;   // stride: 114 dwords == 18 mod 32 -> b64 frag reads conflict-free
  __shared__ __align__(16) unsigned short Kl[196 * 64];  // K rows, chunk-swizzled
  __shared__ __align__(16) unsigned short Vt[64 * WV];   // V^T [d][m], m zero-padded to 224
  const int tid = threadIdx.x, wid = tid >> 6, lane = tid & 63;
  const int s = lane & 15, q = lane >> 4;
  const int bh = blockIdx.x;
  const int b = bh / 12, h = bh % 12;
  const unsigned short* Qb = qkv + (size_t)b * SEQ * QKVLD + h * 64;
  const unsigned short* Kb = Qb + 768;
  const unsigned short* Vb = Qb + 1536;

  // stage K: row r, chunk c (16B); LDS chunk = c ^ gK(r); 8 lanes/row -> 128B coalesced
  {
    const int r0 = tid >> 3, c = tid & 7;
    for (int p = 0; p < 7; ++p) {
      int r = p * 32 + r0;
      if (r < 196) {
        short8 v = *(const short8*)&Kb[(size_t)r * QKVLD + c * 8];
        int gk = ((r >> 3) & 3) ^ ((r & 1) << 2);
        *(short8*)&Kl[r * 64 + ((c ^ gk) << 3)] = v;
      }
    }
  }
  // stage V^T: thread covers m = mb*64 + (tid&63), d = d0..d0+15
  {
    const int ms = tid & 63;
    const int d0 = (tid >> 6) * 16;
    for (int mb = 0; mb < 4; ++mb) {
      int m = mb * 64 + ms;
      if (m < 224) {
        if (m < 196) {
          short8 v0 = *(const short8*)&Vb[(size_t)m * QKVLD + d0];
          short8 v1 = *(const short8*)&Vb[(size_t)m * QKVLD + d0 + 8];
          for (int j = 0; j < 8; j++) Vt[(d0 + j) * WV + m] = (unsigned short)v0[j];
          for (int j = 0; j < 8; j++) Vt[(d0 + 8 + j) * WV + m] = (unsigned short)v1[j];
        } else {
          for (int j = 0; j < 16; j++) Vt[(d0 + j) * WV + m] = 0;
        }
      }
    }
  }
  __syncthreads();

  const int pmbase = (s >> 2) * 8 + (s & 3);   // permuted K-row base for A-frag row s
  const float* saTh = saT + (size_t)h * SEQ * SEQ;

  for (int qt = wid; qt < 13; qt += 4) {
    const int n0 = qt * 16;
    const int nq = n0 + s;
    const int nql = nq > 195 ? 195 : nq;
    short8 qf0 = *(const short8*)&Qb[(size_t)nql * QKVLD + q * 8];
    short8 qf1 = *(const short8*)&Qb[(size_t)nql * QKVLD + 32 + q * 8];

    // S^T tiles: tt = 0..12 (tt = 2t + h4; tile (t=6,h4=1) is entirely m>=196 -> skipped)
    float4v sacc[14];
    for (int tt = 0; tt < 13; tt++) {
      int t = tt >> 1, h4 = tt & 1;
      int m = t * 32 + h4 * 4 + pmbase;
      if (m > 195) m = 195;                       // garbage rows, masked later
      int gk = ((m >> 3) & 3) ^ ((m & 1) << 2);
      short8 kf0 = *(const short8*)&Kl[m * 64 + ((q ^ gk) << 3)];
      short8 kf1 = *(const short8*)&Kl[m * 64 + (((4 + q) ^ gk) << 3)];
      float4v z = (float4v){0.f, 0.f, 0.f, 0.f};
      z = __builtin_amdgcn_mfma_f32_16x16x32_bf16(kf0, qf0, z, 0, 0, 0);
      z = __builtin_amdgcn_mfma_f32_16x16x32_bf16(kf1, qf1, z, 0, 0, 0);
      sacc[tt] = z;
    }
    sacc[13] = (float4v){0.f, 0.f, 0.f, 0.f};

    // column softmax: lane owns column n. Valid m: tt<12 all; tt==12 only q==0.
    float mx = -3.0e38f;
    for (int tt = 0; tt < 12; tt++)
      for (int i = 0; i < 4; i++) mx = fmaxf(mx, sacc[tt][i]);
    if (q == 0)
      for (int i = 0; i < 4; i++) mx = fmaxf(mx, sacc[12][i]);
    mx = fmaxf(mx, __shfl_xor(mx, 16));
    mx = fmaxf(mx, __shfl_xor(mx, 32));
    const float CE = SCALE * 1.44269504f;
    float sm = 0.f;
    for (int tt = 0; tt < 12; tt++)
      for (int i = 0; i < 4; i++) {
        float e = __builtin_amdgcn_exp2f((sacc[tt][i] - mx) * CE);
        sacc[tt][i] = e; sm += e;
      }
    if (q == 0) {
      for (int i = 0; i < 4; i++) {
        float e = __builtin_amdgcn_exp2f((sacc[12][i] - mx) * CE);
        sacc[12][i] = e; sm += e;
      }
    } else {
      sacc[12] = (float4v){0.f, 0.f, 0.f, 0.f};
    }
    sm += __shfl_xor(sm, 16);
    sm += __shfl_xor(sm, 32);
    const float inv = 1.0f / sm;

    // P^T fragments: pfrag[t][j] = P^T[m = t*32 + q*8 + j][n], j = h4*4 + i
    // bias from saT[m][n]: scalar f32 loads, 16 lanes hit 16 consecutive n (coalesced)
    short8 pfrag[7];
    for (int t = 0; t < 7; t++) {
      short8 pf;
      for (int h4 = 0; h4 < 2; h4++) {
        int tt = 2 * t + h4;
        bool valid = (tt < 12) || (tt == 12 && q == 0);
        float a0 = 0.f, a1 = 0.f, a2 = 0.f, a3 = 0.f;
        if (valid) {
          const float* sp = saTh + (size_t)(t * 32 + q * 8 + h4 * 4) * SEQ + nql;
          a0 = sp[0]; a1 = sp[SEQ]; a2 = sp[2 * SEQ]; a3 = sp[3 * SEQ];
        }
        int src = valid ? tt : 13;
        float pv0 = valid ? (sacc[src][0] * inv + a0) : 0.f;
        float pv1 = valid ? (sacc[src][1] * inv + a1) : 0.f;
        float pv2 = valid ? (sacc[src][2] * inv + a2) : 0.f;
        float pv3 = valid ? (sacc[src][3] * inv + a3) : 0.f;
        pf[h4 * 4 + 0] = (short)f2bf(pv0);
        pf[h4 * 4 + 1] = (short)f2bf(pv1);
        pf[h4 * 4 + 2] = (short)f2bf(pv2);
        pf[h4 * 4 + 3] = (short)f2bf(pv3);
      }
      pfrag[t] = pf;
    }

    // O^T = V^T . P^T : A-frag = V^T rows (from LDS, two b64 reads), B-frag = pfrag
    for (int dt = 0; dt < 4; dt++) {
      float4v o = (float4v){0.f, 0.f, 0.f, 0.f};
      for (int t = 0; t < 7; t++) {
        const unsigned short* vp = &Vt[(dt * 16 + s) * WV + t * 32 + q * 8];
        short4v v0 = *(const short4v*)vp;
        short4v v1 = *(const short4v*)(vp + 4);
        short8 vf;
        vf[0] = v0[0]; vf[1] = v0[1]; vf[2] = v0[2]; vf[3] = v0[3];
        vf[4] = v1[0]; vf[5] = v1[1]; vf[6] = v1[2]; vf[7] = v1[3];
        o = __builtin_amdgcn_mfma_f32_16x16x32_bf16(vf, pfrag[t], o, 0, 0, 0);
      }
      // lane holds O^T[d = dt*16 + q*4 + r][n = nq]
      if (nq < 196) {
        ushort4v ov;
        ov.x = f2bf(o[0]); ov.y = f2bf(o[1]); ov.z = f2bf(o[2]); ov.w = f2bf(o[3]);
        *(ushort4v*)&outA[((size_t)b * SEQ + nq) * DIM + h * 64 + dt * 16 + q * 4] = ov;
      }
    }
  }
}

extern "C" void kernel_launch(void* const* d_in, const int* in_sizes, int n_in,
                              void* d_out, int out_size, void* d_ws, size_t ws_size,
                              hipStream_t stream) {
  const float* x        = (const float*)d_in[0];
  const float* Wqkv     = (const float*)d_in[1];
  const float* static_a = (const float*)d_in[2];
  const float* Wproj    = (const float*)d_in[3];
  const float* bproj    = (const float*)d_in[4];
  float* out = (float*)d_out;

  unsigned char* ws = (unsigned char*)d_ws;
  size_t off = 0;
  unsigned short* qkv_ws = (unsigned short*)(ws + off); off += (size_t)NTOK * QKVLD * 2;   // 57.8 MB
  unsigned short* xa_ws  = (unsigned short*)(ws + off); off += (size_t)NTOK * DIM * 2;     // x_bf16, reused as attn-out
  unsigned short* wqkvt  = (unsigned short*)(ws + off); off += (size_t)3 * DIM * DIM * 2;  // W_qkv^T bf16
  unsigned short* wprojt = (unsigned short*)(ws + off); off += (size_t)DIM * DIM * 2;      // W_proj^T bf16
  float* saT_ws          = (float*)(ws + off);          off += (size_t)HEADS * SEQ * SEQ * 4; // 1.84 MB

  cast_x_kernel<<<NTOK * DIM / 4 / 256, 256, 0, stream>>>(x, xa_ws);
  transpose_cast_kernel<<<dim3(3 * DIM / 32, DIM / 32), dim3(32, 8), 0, stream>>>(Wqkv, wqkvt, DIM, 3 * DIM);
  transpose_cast_kernel<<<dim3(DIM / 32, DIM / 32), dim3(32, 8), 0, stream>>>(Wproj, wprojt, DIM, DIM);
  transpose_sa_kernel<<<dim3(7, 7, HEADS), dim3(32, 8), 0, stream>>>(static_a, saT_ws);
  gemm256_kernel<0><<<dim3(3 * DIM / 256, NTOK / 256), 512, 0, stream>>>(xa_ws, wqkvt, nullptr, qkv_ws, nullptr);
  attn_kernel<<<BATCH * HEADS, 256, 0, stream>>>(qkv_ws, saT_ws, xa_ws);
  gemm256_kernel<1><<<dim3(DIM / 256, NTOK / 256), 512, 0, stream>>>(xa_ws, wprojt, bproj, nullptr, out);
}